// Round 4
// baseline (17197.571 us; speedup 1.0000x reference)
//
#include <hip/hip_runtime.h>

// ---------------- problem constants ----------------
#define NLAYER 64
#define HID    50
#define DIN    60
#define DOUT   50
#define BATCH  32
#define NT     2048
#define NG     200          // 4*HID
#define DEPTH  16           // ring depth (power of two)
#define BS     8            // batch slice per block (BATCH/4)
#define FUEL   (1 << 16)    // spin bound: stall -> wrong results, not a hang

// ---------------- workspace layout ----------------
// prod u32[256] @0 ; cons u32[256] @1024 ; ring @4096 ; y63 after ring
#define RING_OFF   4096
#define SLOT_F     512                                   // 8 rows x 64 floats
#define RING_BYTES ((size_t)256*DEPTH*SLOT_F*4)          // 8 MiB  [(l,q) x 16 slots]
#define Y63_OFF    (RING_OFF + RING_BYTES)

// ---------------- output layout ----------------
#define HS_OFF ((size_t)BATCH*DOUT*NT)                   // 3,276,800
#define CS_OFF (HS_OFF + (size_t)NLAYER*BATCH*HID)       // +102,400

typedef float f4 __attribute__((ext_vector_type(4)));
typedef unsigned long long u64;

// agent-scope (cross-XCD coherent) relaxed atomics — compiler-tracked
#define AL(p)   __hip_atomic_load((p),  __ATOMIC_RELAXED, __HIP_MEMORY_SCOPE_AGENT)
#define AS(p,v) __hip_atomic_store((p), (v), __ATOMIC_RELAXED, __HIP_MEMORY_SCOPE_AGENT)

__device__ __forceinline__ float sigf(float v)  { return 1.f / (1.f + __expf(-v)); }
__device__ __forceinline__ float tanhx(float v) { return 2.f / (1.f + __expf(-2.f*v)) - 1.f; }

// broadcast x[b][k] from bulk-loaded wave-distributed chunks via readlane
__device__ __forceinline__ float bcast(const f4& A, const f4& B, int c, int j) {
  float s = (c < 64) ? A[j] : B[j];                 // c, j compile-time after unroll
  return __uint_as_float(__builtin_amdgcn_readlane(__float_as_uint(s), c & 63));
}

template<int KX>
__device__ __forceinline__ void dotk(const f4& A, const f4& B,
                                     const float* __restrict__ w,
                                     float* __restrict__ acc) {
#pragma unroll
  for (int k = 0; k < KX; ++k) {
    const int c0 = k >> 2, j = k & 3;
#pragma unroll
    for (int b = 0; b < 8; ++b)
      acc[b] = fmaf(bcast(A, B, b*16 + c0, j), w[k], acc[b]);
  }
}

// =====================================================================
// Persistent pipelined LSTM: 256 blocks = 64 layers x 4 batch-quarters.
// lane = gate-row (r=1): 110 weight f32/thread pinned in VGPRs (opaque via asm).
// x/h bulk ds_read once/wave -> readlane broadcast GEMM (per-SIMD VALU pipe).
// Depth-2 prefetch + deferred ring stores: LLC latency hidden under GEMM.
// =====================================================================
__global__ __launch_bounds__(256, 1) void lstm_pipe(
    const float* __restrict__ x,   const float* __restrict__ hn,
    const float* __restrict__ cn,  const float* __restrict__ Wih0,
    const float* __restrict__ Wih, const float* __restrict__ Whh,
    const float* __restrict__ bih, const float* __restrict__ bhh,
    unsigned* prod, unsigned* cons, float* ring, float* y63, float* out)
{
  __shared__ f4 x4[128];               // x(t): 8 rows x 64 floats (pads zeroed)
  __shared__ f4 h4[128];               // h(t-1): 8 rows x 64 floats (pads zeroed)
  __shared__ float g_lds[8*NG];        // gates [b][row]
  float* x_lds = (float*)x4;
  float* h_lds = (float*)h4;

  const int tid  = threadIdx.x;
  const int lane = tid & 63;
  const int bid  = blockIdx.x;
  const int xcd = bid & 7, jj = bid >> 3;        // layer->XCD grouping (perf only)
  const int l = xcd*8 + (jj >> 2);
  const int q = jj & 3;
  const int r = tid;                             // gate row (active r<200)
  const int KPAD = (l == 0) ? DIN : HID;

  // ---------- prologue: weights + cell state into registers ----------
  float wih[60], whh[50];
  float bias_r = 0.f, c0 = 0.f, c1 = 0.f;
  if (r < NG) {
    if (l == 0) {
#pragma unroll
      for (int k = 0; k < 60; ++k) wih[k] = Wih0[r*DIN + k];
    } else {
      const float* wr = Wih + ((size_t)(l-1)*NG + r)*HID;
#pragma unroll
      for (int k = 0; k < 60; ++k) wih[k] = (k < HID) ? wr[k] : 0.f;
    }
    const float* hr = Whh + ((size_t)l*NG + r)*HID;
#pragma unroll
    for (int k = 0; k < 50; ++k) whh[k] = hr[k];
    bias_r = bih[l*NG + r] + bhh[l*NG + r];
    const int u1 = tid, u2 = tid + 200;          // cell ids (b*50+j)
    c0 = cn[((size_t)l*BATCH + q*BS + u1/HID)*HID + u1%HID];
    c1 = cn[((size_t)l*BATCH + q*BS + u2/HID)*HID + u2%HID];
  } else {
#pragma unroll
    for (int k = 0; k < 60; ++k) wih[k] = 0.f;
#pragma unroll
    for (int k = 0; k < 50; ++k) whh[k] = 0.f;
  }
  // pin weights in VGPRs: opaque values -> compiler cannot remat-from-memory
#pragma unroll
  for (int k = 0; k < 60; ++k) asm volatile("" : "+v"(wih[k]));
#pragma unroll
  for (int k = 0; k < 50; ++k) asm volatile("" : "+v"(whh[k]));
  asm volatile("" : "+v"(bias_r));

  // h(-1) into h_lds (pads zero)
  for (int idx = tid; idx < 512; idx += 256) {
    const int b = idx >> 6, j = idx & 63;
    h_lds[idx] = (j < HID) ? hn[((size_t)l*BATCH + q*BS + b)*HID + j] : 0.f;
  }

  const unsigned* prod_in   = prod + ((l-1)*4 + q);   // deref only if l>0
  unsigned*       prod_out  = prod + (l*4 + q);
  unsigned*       cons_self = cons + (l*4 + q);
  const unsigned* cons_next = cons + ((l+1)*4 + q);   // deref only if l<63

  float*       ring_out = ring + ((size_t)(l*4 + q))*DEPTH*SLOT_F;
  const float* ring_in  = ring + ((size_t)((l-1)*4 + q))*DEPTH*SLOT_F;

  const int e0 = 2*tid, e1 = e0 + 1;
  const int d0_ = e0 & 63, d1_ = d0_ + 1, eb = e0 >> 6;   // row b of element pair

  // ---------- prologue: x(0) -> x_lds ; fx = x(1) ----------
  float fx0 = 0.f, fx1 = 0.f;
  if (l == 0) {
    x_lds[e0] = (d0_ < DIN) ? x[((size_t)(q*BS + eb)*DIN + d0_)*NT + 0] : 0.f;
    x_lds[e1] = (d1_ < DIN) ? x[((size_t)(q*BS + eb)*DIN + d1_)*NT + 0] : 0.f;
    fx0 = (d0_ < DIN) ? x[((size_t)(q*BS + eb)*DIN + d0_)*NT + 1] : 0.f;
    fx1 = (d1_ < DIN) ? x[((size_t)(q*BS + eb)*DIN + d1_)*NT + 1] : 0.f;
  } else {
    const u64* rin64 = (const u64*)ring_in;
    int fuel = FUEL;
    while (AL(prod_in) < 1u && --fuel) __builtin_amdgcn_s_sleep(4);
    u64 v0 = AL(rin64 + tid);
    x_lds[e0] = (d0_ < HID) ? __uint_as_float((unsigned)v0) : 0.f;
    x_lds[e1] = (d1_ < HID) ? __uint_as_float((unsigned)(v0 >> 32)) : 0.f;
    fuel = FUEL;
    while (AL(prod_in) < 2u && --fuel) __builtin_amdgcn_s_sleep(4);
    u64 v1 = AL(rin64 + SLOT_F/2 + tid);
    fx0 = __uint_as_float((unsigned)v1);
    fx1 = __uint_as_float((unsigned)(v1 >> 32));
    if (tid == 0) AS(cons_self, 2u);
  }
  __syncthreads();

  unsigned c_c = 0;                    // last-polled consumer progress (1-step stale)
  float hh0 = 0.f, hh1 = 0.f;          // h(t-1) held for deferred ring store

  for (int t = 0; t < NT; ++t) {
    // A: bulk read x(t), h(t-1) into regs (4x ds_read_b128, conflict-free)
    f4 vxA = x4[lane], vxB = x4[lane + 64];
    f4 vhA = h4[lane], vhB = h4[lane + 64];

    // C: deferred ring store of h(t-1) (slot (t-1)&15; wrap-reuse guard)
    if (l < 63 && t >= 1) {
      int fuel = FUEL;
      while ((int)c_c < t - 16 && --fuel) {              // rare (rate-matching)
        c_c = AL(cons_next);
        if ((int)c_c < t - 16) __builtin_amdgcn_s_sleep(4);
      }
      if (tid < NG) {
        unsigned* sb = (unsigned*)(ring_out + ((t-1) & (DEPTH-1))*SLOT_F);
        AS(sb + (tid/HID)*64     + tid%HID, __float_as_uint(hh0));
        AS(sb + (tid/HID + 4)*64 + tid%HID, __float_as_uint(hh1));
      }
    }

    // B: issue polls (results used ~3.5kcy later -> LLC latency hidden by GEMM)
    unsigned p_c2 = 0, c_c2 = c_c;
    if (l > 0 && t + 2 < NT) p_c2 = AL(prod_in);
    if (l < 63)              c_c2 = AL(cons_next);

    // D: GEMM  gates[b][r] = bias + Wih.x + Whh.h   (registers only)
    float acc[8];
#pragma unroll
    for (int b = 0; b < 8; ++b) acc[b] = bias_r;
    if (l == 0) dotk<60>(vxA, vxB, wih, acc);
    else        dotk<50>(vxA, vxB, wih, acc);
    dotk<50>(vhA, vhB, whh, acc);
    if (r < NG) {
#pragma unroll
      for (int b = 0; b < 8; ++b) g_lds[b*NG + r] = acc[b];
    }
    __syncthreads();   // E: gates visible; drains C-stores + B-polls + old fx loads

    // F: x_lds <- fx (= x(t+1)), pads zeroed
    if (t + 1 < NT) {
      x_lds[e0] = (d0_ < KPAD) ? fx0 : 0.f;
      x_lds[e1] = (d1_ < KPAD) ? fx1 : 0.f;
    }

    // G: publish progress (h(0..t-1) at LLC since E drained; x(t+1) extracted)
    if (tid == 0) {
      if (l < 63 && t >= 1) AS(prod_out, (unsigned)t);
      if (l > 0)            AS(cons_self, (unsigned)(t + 2));
    }

    // H: prefetch x(t+2) into fx (drains at next E, used at next F)
    if (t + 2 < NT) {
      if (l == 0) {
        fx0 = (d0_ < DIN) ? x[((size_t)(q*BS + eb)*DIN + d0_)*NT + (t+2)] : 0.f;
        fx1 = (d1_ < DIN) ? x[((size_t)(q*BS + eb)*DIN + d1_)*NT + (t+2)] : 0.f;
      } else {
        int fuel = FUEL;
        while (p_c2 < (unsigned)(t + 3) && --fuel) {     // rare (rate-matching)
          p_c2 = AL(prod_in);
          if (p_c2 < (unsigned)(t + 3)) __builtin_amdgcn_s_sleep(4);
        }
        const u64* lb = (const u64*)(ring_in + ((t+2) & (DEPTH-1))*SLOT_F);
        u64 v = AL(lb + tid);
        fx0 = __uint_as_float((unsigned)v);
        fx1 = __uint_as_float((unsigned)(v >> 32));
      }
    }

    // I: elementwise LSTM update (2 cells/thread, c in regs)
    if (tid < NG) {
#pragma unroll
      for (int half = 0; half < 2; ++half) {
        const int u = tid + half*200;
        const int b = u / HID, j = u % HID;
        const float cprev = half ? c1 : c0;
        const float gi = g_lds[b*NG +            j];
        const float gf = g_lds[b*NG +  50 +      j];
        const float gg = g_lds[b*NG + 100 +      j];
        const float go = g_lds[b*NG + 150 +      j];
        const float cc = sigf(gf)*cprev + sigf(gi)*tanhx(gg);
        const float hh = sigf(go)*tanhx(cc);
        if (half) { c1 = cc; hh1 = hh; } else { c0 = cc; hh0 = hh; }
        h_lds[b*64 + j] = hh;
        const int bg = q*BS + b;
        if (l == 63)
          y63[((size_t)t*BATCH + bg)*HID + j] = hh;
        if (t == NT-1) {
          out[HS_OFF + (size_t)l*BATCH*HID + bg*HID + j] = hh;
          out[CS_OFF + (size_t)l*BATCH*HID + bg*HID + j] = cc;
        }
      }
    }
    c_c = c_c2;
    __syncthreads();   // J: h_lds/x_lds ready for next A; g_lds reusable
  }

  // epilogue: ship h(NT-1) to the ring and publish completion
  if (l < 63) {
    int fuel = FUEL;
    while ((int)c_c < NT - 16 && --fuel) {
      c_c = AL(cons_next);
      if ((int)c_c < NT - 16) __builtin_amdgcn_s_sleep(4);
    }
    if (tid < NG) {
      unsigned* sb = (unsigned*)(ring_out + ((NT-1) & (DEPTH-1))*SLOT_F);
      AS(sb + (tid/HID)*64     + tid%HID, __float_as_uint(hh0));
      AS(sb + (tid/HID + 4)*64 + tid%HID, __float_as_uint(hh1));
    }
    __syncthreads();   // drain stores before publishing
    if (tid == 0) AS(prod_out, (unsigned)NT);
  }
}

// =====================================================================
// FC head: out[b][d][t] = sigmoid(y63[t][b][:] . fc_w[d][:] + fc_b[d])
// =====================================================================
__global__ __launch_bounds__(320, 1) void fc_kernel(
    const float* __restrict__ y63, const float* __restrict__ fcw,
    const float* __restrict__ fcb, float* __restrict__ out)
{
  __shared__ float y_lds[64*52];
  __shared__ float w_lds[50*52];
  __shared__ float b_lds[50];
  const int tid = threadIdx.x;
  const int b  = blockIdx.x >> 5;
  const int t0 = (blockIdx.x & 31) * 64;
  for (int idx = tid; idx < 64*52; idx += 320) {
    const int rr = idx / 52, j = idx % 52;
    y_lds[idx] = (j < HID) ? y63[((size_t)(t0 + rr)*BATCH + b)*HID + j] : 0.f;
  }
  for (int idx = tid; idx < 50*52; idx += 320) {
    const int rr = idx / 52, j = idx % 52;
    w_lds[idx] = (j < HID) ? fcw[rr*HID + j] : 0.f;
  }
  if (tid < 50) b_lds[tid] = fcb[tid];
  __syncthreads();
  const int toff = tid & 63, dg = tid >> 6;   // dg in [0,5)
  for (int d = dg; d < DOUT; d += 5) {
    float acc = b_lds[d];
#pragma unroll
    for (int j4 = 0; j4 < 13; ++j4) {
      f4 yv = *(const f4*)&y_lds[toff*52 + j4*4];
      f4 wv = *(const f4*)&w_lds[d*52 + j4*4];
#pragma unroll
      for (int j = 0; j < 4; ++j) acc = fmaf(yv[j], wv[j], acc);
    }
    out[((size_t)b*DOUT + d)*NT + t0 + toff] = 1.f / (1.f + __expf(-acc));
  }
}

extern "C" void kernel_launch(void* const* d_in, const int* in_sizes, int n_in,
                              void* d_out, int out_size, void* d_ws, size_t ws_size,
                              hipStream_t stream)
{
  const float* x    = (const float*)d_in[0];
  const float* hn   = (const float*)d_in[1];
  const float* cn   = (const float*)d_in[2];
  const float* Wih0 = (const float*)d_in[3];
  const float* Wih  = (const float*)d_in[4];
  const float* Whh  = (const float*)d_in[5];
  const float* bih  = (const float*)d_in[6];
  const float* bhh  = (const float*)d_in[7];
  const float* fcw  = (const float*)d_in[8];
  const float* fcb  = (const float*)d_in[9];
  float* out = (float*)d_out;

  unsigned* prod = (unsigned*)d_ws;
  unsigned* cons = (unsigned*)((char*)d_ws + 1024);
  float*    ring = (float*)((char*)d_ws + RING_OFF);
  float*    y63  = (float*)((char*)d_ws + Y63_OFF);
  (void)in_sizes; (void)n_in; (void)out_size; (void)ws_size;

  // prod/cons counters must start at zero (ws is re-poisoned 0xAA each call)
  hipMemsetAsync(d_ws, 0, 4096, stream);

  hipLaunchKernelGGL(lstm_pipe, dim3(256), dim3(256), 0, stream,
                     x, hn, cn, Wih0, Wih, Whh, bih, bhh,
                     prod, cons, ring, y63, out);
  hipLaunchKernelGGL(fc_kernel, dim3(1024), dim3(320), 0, stream, y63, fcw, fcb, out);
}